// Round 1
// baseline (1863.140 us; speedup 1.0000x reference)
//
#include <hip/hip_runtime.h>
#include <cstdint>
#include <cstddef>

#define D 128
#define O2 64

__device__ inline void atomAdd(float* p, float v) { unsafeAtomicAdd(p, v); }

// Scatter-add feat[src[e]] into agg[dst[e]], row width = W4 float4s.
// Optionally counts edges per dst (lane 0) into cnt.
template<int W4>
__global__ __launch_bounds__(256) void scatter_kernel(
    const float* __restrict__ feat, const int* __restrict__ src,
    const int* __restrict__ dst, float* __restrict__ agg,
    float* __restrict__ cnt, int n_edges)
{
  const int epb = 256 / W4;
  int e = blockIdx.x * epb + (threadIdx.x / W4);
  if (e >= n_edges) return;
  int lane = threadIdx.x & (W4 - 1);
  int s = src[e], d = dst[e];
  float4 v = ((const float4*)feat)[(size_t)s * W4 + lane];
  float* o = agg + ((size_t)d * W4 + lane) * 4;
  atomAdd(o + 0, v.x); atomAdd(o + 1, v.y);
  atomAdd(o + 2, v.z); atomAdd(o + 3, v.w);
  if (cnt && lane == 0) atomAdd(cnt + d, 1.0f);
}

// h[n] = relu( (agg[n]/max(cnt,1)) @ W1l + b1l + x[n] @ W1r )
// 32 nodes/block, thread = (j in 0..63, group g in 0..3), 8 nodes x 2 cols per thread.
__global__ __launch_bounds__(256) void layer1_kernel(
    const float* __restrict__ x, const float* __restrict__ agg,
    const float* __restrict__ cnt, const float* __restrict__ WlT,
    const float* __restrict__ bl, const float* __restrict__ WrT,
    float* __restrict__ h, int n_nodes)
{
  __shared__ float s_a[32][D];
  __shared__ float s_x[32][D];
  __shared__ float s_ic[32];
  const int t = threadIdx.x;
  const int n0 = blockIdx.x * 32;
  if (t < 32) {
    int n = n0 + t;
    float c = (n < n_nodes) ? cnt[n] : 1.0f;
    s_ic[t] = 1.0f / fmaxf(c, 1.0f);
  }
  __syncthreads();
  for (int e = t; e < 32 * D; e += 256) {
    int i = e >> 7, k = e & (D - 1);
    int n = n0 + i;
    float av = 0.f, xv = 0.f;
    if (n < n_nodes) {
      av = agg[(size_t)n * D + k] * s_ic[i];
      xv = x[(size_t)n * D + k];
    }
    s_a[i][k] = av;
    s_x[i][k] = xv;
  }
  __syncthreads();
  const int j = t & 63;
  const int g = t >> 6;
  float acc0[8], acc1[8];
  float b0 = bl[j], b1 = bl[j + 64];
  #pragma unroll
  for (int m = 0; m < 8; m++) { acc0[m] = b0; acc1[m] = b1; }
  const float4* wl0 = (const float4*)(WlT + (size_t)j * D);
  const float4* wl1 = (const float4*)(WlT + (size_t)(j + 64) * D);
  const float4* wr0 = (const float4*)(WrT + (size_t)j * D);
  const float4* wr1 = (const float4*)(WrT + (size_t)(j + 64) * D);
  for (int k4 = 0; k4 < D / 4; k4++) {
    float4 vl0 = wl0[k4], vl1 = wl1[k4];
    float4 vr0 = wr0[k4], vr1 = wr1[k4];
    #pragma unroll
    for (int m = 0; m < 8; m++) {
      float4 a  = *(const float4*)&s_a[g * 8 + m][k4 * 4];
      float4 xx = *(const float4*)&s_x[g * 8 + m][k4 * 4];
      acc0[m] += a.x*vl0.x + a.y*vl0.y + a.z*vl0.z + a.w*vl0.w
               + xx.x*vr0.x + xx.y*vr0.y + xx.z*vr0.z + xx.w*vr0.w;
      acc1[m] += a.x*vl1.x + a.y*vl1.y + a.z*vl1.z + a.w*vl1.w
               + xx.x*vr1.x + xx.y*vr1.y + xx.z*vr1.z + xx.w*vr1.w;
    }
  }
  #pragma unroll
  for (int m = 0; m < 8; m++) {
    int n = n0 + g * 8 + m;
    if (n < n_nodes) {
      h[(size_t)n * D + j]      = fmaxf(acc0[m], 0.f);
      h[(size_t)n * D + j + 64] = fmaxf(acc1[m], 0.f);
    }
  }
}

// out[n] = in[n] @ WT^T  (+ bias + aggadd[n]/max(cnt,1) when FINAL)
// 64 nodes/block, thread = (j in 0..31, group g in 0..7), 8 nodes x 2 cols per thread.
template<bool FINAL>
__global__ __launch_bounds__(256) void gemm64_kernel(
    const float* __restrict__ in, const float* __restrict__ WT,
    const float* __restrict__ bias, const float* __restrict__ aggadd,
    const float* __restrict__ cnt, float* __restrict__ out, int n_nodes)
{
  __shared__ float s_in[64][D];
  const int t = threadIdx.x;
  const int n0 = blockIdx.x * 64;
  for (int e = t; e < 64 * D; e += 256) {
    int i = e >> 7, k = e & (D - 1);
    int n = n0 + i;
    s_in[i][k] = (n < n_nodes) ? in[(size_t)n * D + k] : 0.f;
  }
  __syncthreads();
  const int j = t & 31;
  const int g = t >> 5;
  float acc0[8], acc1[8];
  #pragma unroll
  for (int m = 0; m < 8; m++) { acc0[m] = 0.f; acc1[m] = 0.f; }
  const float4* w0 = (const float4*)(WT + (size_t)j * D);
  const float4* w1 = (const float4*)(WT + (size_t)(j + 32) * D);
  for (int k4 = 0; k4 < D / 4; k4++) {
    float4 v0 = w0[k4], v1 = w1[k4];
    #pragma unroll
    for (int m = 0; m < 8; m++) {
      float4 a = *(const float4*)&s_in[g * 8 + m][k4 * 4];
      acc0[m] += a.x*v0.x + a.y*v0.y + a.z*v0.z + a.w*v0.w;
      acc1[m] += a.x*v1.x + a.y*v1.y + a.z*v1.z + a.w*v1.w;
    }
  }
  #pragma unroll
  for (int m = 0; m < 8; m++) {
    int n = n0 + g * 8 + m;
    if (n < n_nodes) {
      float o0 = acc0[m], o1 = acc1[m];
      if (FINAL) {
        float ic = 1.0f / fmaxf(cnt[n], 1.0f);
        o0 += bias[j]      + aggadd[(size_t)n * O2 + j] * ic;
        o1 += bias[j + 32] + aggadd[(size_t)n * O2 + j + 32] * ic;
      }
      out[(size_t)n * O2 + j]      = o0;
      out[(size_t)n * O2 + j + 32] = o1;
    }
  }
}

// Transpose the four weight matrices into workspace (row-major [out_col][k]).
__global__ __launch_bounds__(256) void transpose_w(
    const float* __restrict__ W1l, const float* __restrict__ W1r,
    const float* __restrict__ W2l, const float* __restrict__ W2r,
    float* __restrict__ W1lT, float* __restrict__ W1rT,
    float* __restrict__ W2lT, float* __restrict__ W2rT)
{
  int t = blockIdx.x * 256 + threadIdx.x;
  if (t < 16384) { int r = t >> 7, c = t & 127; W1lT[c * 128 + r] = W1l[t]; }
  else if (t < 32768) { int u = t - 16384; int r = u >> 7, c = u & 127; W1rT[c * 128 + r] = W1r[u]; }
  else if (t < 40960) { int u = t - 32768; int r = u >> 6, c = u & 63; W2lT[c * 128 + r] = W2l[u]; }
  else if (t < 49152) { int u = t - 40960; int r = u >> 6, c = u & 63; W2rT[c * 128 + r] = W2r[u]; }
}

extern "C" void kernel_launch(void* const* d_in, const int* in_sizes, int n_in,
                              void* d_out, int out_size, void* d_ws, size_t ws_size,
                              hipStream_t stream)
{
  const float* x   = (const float*)d_in[0];
  const int*   ei  = (const int*)d_in[1];
  const float* W1l = (const float*)d_in[2];
  const float* b1l = (const float*)d_in[3];
  const float* W1r = (const float*)d_in[4];
  const float* W2l = (const float*)d_in[5];
  const float* b2l = (const float*)d_in[6];
  const float* W2r = (const float*)d_in[7];
  float* out = (float*)d_out;

  const int n_nodes = in_sizes[0] / D;   // 50000
  const int n_edges = in_sizes[1] / 2;   // 600000
  const int* src = ei;
  const int* dst = ei + n_edges;

  char* ws = (char*)d_ws;
  const size_t sz_cnt  = ((size_t)n_nodes * 4 + 255) & ~(size_t)255;
  const size_t sz_agg  = (size_t)n_nodes * D * 4;
  const size_t sz_hl   = (size_t)n_nodes * O2 * 4;
  const size_t off_cnt = 0;
  const size_t off_agg = off_cnt + sz_cnt;
  const size_t off_h   = off_agg + sz_agg;
  const size_t off_hl  = off_h + sz_agg;
  const size_t off_wt  = off_hl + sz_hl;

  float* cnt  = (float*)(ws + off_cnt);
  float* agg  = (float*)(ws + off_agg);   // reused as 64-wide agg for layer 2
  float* h    = (float*)(ws + off_h);
  float* hl   = (float*)(ws + off_hl);
  float* W1lT = (float*)(ws + off_wt);
  float* W1rT = W1lT + 128 * 128;
  float* W2lT = W1rT + 128 * 128;
  float* W2rT = W2lT + 128 * 64;

  // zero cnt + agg (contiguous)
  hipMemsetAsync(ws + off_cnt, 0, sz_cnt + sz_agg, stream);

  transpose_w<<<192, 256, 0, stream>>>(W1l, W1r, W2l, W2r, W1lT, W1rT, W2lT, W2rT);

  // layer 1 aggregation: agg = segment_sum(x[src]) at dst; cnt = degree
  scatter_kernel<32><<<(n_edges + 7) / 8, 256, 0, stream>>>(x, src, dst, agg, cnt, n_edges);

  // h = relu(mean @ W1l + b1l + x @ W1r)
  layer1_kernel<<<(n_nodes + 31) / 32, 256, 0, stream>>>(x, agg, cnt, W1lT, b1l, W1rT, h, n_nodes);

  // hl = h @ W2l  (push matmul before aggregation: scatter only 64 wide)
  gemm64_kernel<false><<<(n_nodes + 63) / 64, 256, 0, stream>>>(
      h, W2lT, nullptr, nullptr, nullptr, hl, n_nodes);

  // layer 2 aggregation on hl (64-wide)
  hipMemsetAsync(agg, 0, (size_t)n_nodes * O2 * 4, stream);
  scatter_kernel<16><<<(n_edges + 15) / 16, 256, 0, stream>>>(hl, src, dst, agg, nullptr, n_edges);

  // out = agg/max(cnt,1) + b2l + h @ W2r
  gemm64_kernel<true><<<(n_nodes + 63) / 64, 256, 0, stream>>>(
      h, W2rT, b2l, agg, cnt, out, n_nodes);
}

// Round 2
// 567.520 us; speedup vs baseline: 3.2829x; 3.2829x over previous
//
#include <hip/hip_runtime.h>
#include <cstdint>
#include <cstddef>

#define D 128
#define O2 64

// ---------------- CSR build ----------------

__global__ __launch_bounds__(256) void hist_kernel(
    const int* __restrict__ dst, int* __restrict__ deg, int n_edges)
{
  int e = blockIdx.x * 256 + threadIdx.x;
  if (e < n_edges) atomicAdd(&deg[dst[e]], 1);
}

// Single-block exclusive scan over deg -> off, cursor copy, invdeg.
__global__ __launch_bounds__(1024) void scan_kernel(
    const int* __restrict__ deg, int* __restrict__ off, int* __restrict__ cursor,
    float* __restrict__ invdeg, int n_nodes)
{
  __shared__ int part[1024];
  const int t = threadIdx.x;
  const int chunk = (n_nodes + 1023) / 1024;
  const int lo = t * chunk;
  const int hi = min(lo + chunk, n_nodes);
  int s = 0;
  for (int i = lo; i < hi; i++) s += deg[i];
  part[t] = s;
  __syncthreads();
  for (int d = 1; d < 1024; d <<= 1) {
    int v = (t >= d) ? part[t - d] : 0;
    __syncthreads();
    part[t] += v;
    __syncthreads();
  }
  int run = (t == 0) ? 0 : part[t - 1];
  for (int i = lo; i < hi; i++) {
    off[i] = run; cursor[i] = run;
    int dg = deg[i];
    invdeg[i] = 1.0f / fmaxf((float)dg, 1.0f);
    run += dg;
  }
  if (t == 1023) off[n_nodes] = run;
}

__global__ __launch_bounds__(256) void fill_kernel(
    const int* __restrict__ src, const int* __restrict__ dst,
    int* __restrict__ cursor, int* __restrict__ eidx, int n_edges)
{
  int e = blockIdx.x * 256 + threadIdx.x;
  if (e < n_edges) {
    int p = atomicAdd(&cursor[dst[e]], 1);
    eidx[p] = src[e];
  }
}

// ---------------- gather aggregation (mean folded) ----------------
// W4 = float4s per row. 256/W4 nodes per block.
template<int W4>
__global__ __launch_bounds__(256) void gather_mean_kernel(
    const float* __restrict__ feat, const int* __restrict__ eidx,
    const int* __restrict__ off, const float* __restrict__ invdeg,
    float* __restrict__ mean, int n_nodes)
{
  const int npb = 256 / W4;
  int g = threadIdx.x / W4;
  int j = threadIdx.x & (W4 - 1);
  int n = blockIdx.x * npb + g;
  if (n >= n_nodes) return;
  int lo = off[n], hi = off[n + 1];
  float4 acc = {0.f, 0.f, 0.f, 0.f};
  for (int p = lo; p < hi; p++) {
    int s = eidx[p];
    float4 v = ((const float4*)feat)[(size_t)s * W4 + j];
    acc.x += v.x; acc.y += v.y; acc.z += v.z; acc.w += v.w;
  }
  float ic = invdeg[n];
  acc.x *= ic; acc.y *= ic; acc.z *= ic; acc.w *= ic;
  ((float4*)mean)[(size_t)n * W4 + j] = acc;
}

// ---------------- layer 1 fused GEMM ----------------
// h[n] = relu( mean[n] @ W1l + b1l + x[n] @ W1r )
__global__ __launch_bounds__(256) void layer1_kernel(
    const float* __restrict__ x, const float* __restrict__ mean,
    const float* __restrict__ WlT, const float* __restrict__ bl,
    const float* __restrict__ WrT, float* __restrict__ h, int n_nodes)
{
  __shared__ float s_a[32][D];
  __shared__ float s_x[32][D];
  const int t = threadIdx.x;
  const int n0 = blockIdx.x * 32;
  for (int e = t; e < 32 * D; e += 256) {
    int i = e >> 7, k = e & (D - 1);
    int n = n0 + i;
    float av = 0.f, xv = 0.f;
    if (n < n_nodes) {
      av = mean[(size_t)n * D + k];
      xv = x[(size_t)n * D + k];
    }
    s_a[i][k] = av;
    s_x[i][k] = xv;
  }
  __syncthreads();
  const int j = t & 63;
  const int g = t >> 6;
  float acc0[8], acc1[8];
  float b0 = bl[j], b1 = bl[j + 64];
  #pragma unroll
  for (int m = 0; m < 8; m++) { acc0[m] = b0; acc1[m] = b1; }
  const float4* wl0 = (const float4*)(WlT + (size_t)j * D);
  const float4* wl1 = (const float4*)(WlT + (size_t)(j + 64) * D);
  const float4* wr0 = (const float4*)(WrT + (size_t)j * D);
  const float4* wr1 = (const float4*)(WrT + (size_t)(j + 64) * D);
  for (int k4 = 0; k4 < D / 4; k4++) {
    float4 vl0 = wl0[k4], vl1 = wl1[k4];
    float4 vr0 = wr0[k4], vr1 = wr1[k4];
    #pragma unroll
    for (int m = 0; m < 8; m++) {
      float4 a  = *(const float4*)&s_a[g * 8 + m][k4 * 4];
      float4 xx = *(const float4*)&s_x[g * 8 + m][k4 * 4];
      acc0[m] += a.x*vl0.x + a.y*vl0.y + a.z*vl0.z + a.w*vl0.w
               + xx.x*vr0.x + xx.y*vr0.y + xx.z*vr0.z + xx.w*vr0.w;
      acc1[m] += a.x*vl1.x + a.y*vl1.y + a.z*vl1.z + a.w*vl1.w
               + xx.x*vr1.x + xx.y*vr1.y + xx.z*vr1.z + xx.w*vr1.w;
    }
  }
  #pragma unroll
  for (int m = 0; m < 8; m++) {
    int n = n0 + g * 8 + m;
    if (n < n_nodes) {
      h[(size_t)n * D + j]      = fmaxf(acc0[m], 0.f);
      h[(size_t)n * D + j + 64] = fmaxf(acc1[m], 0.f);
    }
  }
}

// ---------------- 128->64 GEMM ----------------
// out[n] = in[n] @ WT^T (+ bias + aggmean[n] when FINAL; aggmean pre-scaled)
template<bool FINAL>
__global__ __launch_bounds__(256) void gemm64_kernel(
    const float* __restrict__ in, const float* __restrict__ WT,
    const float* __restrict__ bias, const float* __restrict__ aggmean,
    float* __restrict__ out, int n_nodes)
{
  __shared__ float s_in[64][D];
  const int t = threadIdx.x;
  const int n0 = blockIdx.x * 64;
  for (int e = t; e < 64 * D; e += 256) {
    int i = e >> 7, k = e & (D - 1);
    int n = n0 + i;
    s_in[i][k] = (n < n_nodes) ? in[(size_t)n * D + k] : 0.f;
  }
  __syncthreads();
  const int j = t & 31;
  const int g = t >> 5;
  float acc0[8], acc1[8];
  #pragma unroll
  for (int m = 0; m < 8; m++) { acc0[m] = 0.f; acc1[m] = 0.f; }
  const float4* w0 = (const float4*)(WT + (size_t)j * D);
  const float4* w1 = (const float4*)(WT + (size_t)(j + 32) * D);
  for (int k4 = 0; k4 < D / 4; k4++) {
    float4 v0 = w0[k4], v1 = w1[k4];
    #pragma unroll
    for (int m = 0; m < 8; m++) {
      float4 a = *(const float4*)&s_in[g * 8 + m][k4 * 4];
      acc0[m] += a.x*v0.x + a.y*v0.y + a.z*v0.z + a.w*v0.w;
      acc1[m] += a.x*v1.x + a.y*v1.y + a.z*v1.z + a.w*v1.w;
    }
  }
  #pragma unroll
  for (int m = 0; m < 8; m++) {
    int n = n0 + g * 8 + m;
    if (n < n_nodes) {
      float o0 = acc0[m], o1 = acc1[m];
      if (FINAL) {
        o0 += bias[j]      + aggmean[(size_t)n * O2 + j];
        o1 += bias[j + 32] + aggmean[(size_t)n * O2 + j + 32];
      }
      out[(size_t)n * O2 + j]      = o0;
      out[(size_t)n * O2 + j + 32] = o1;
    }
  }
}

// ---------------- weight transpose ----------------
__global__ __launch_bounds__(256) void transpose_w(
    const float* __restrict__ W1l, const float* __restrict__ W1r,
    const float* __restrict__ W2l, const float* __restrict__ W2r,
    float* __restrict__ W1lT, float* __restrict__ W1rT,
    float* __restrict__ W2lT, float* __restrict__ W2rT)
{
  int t = blockIdx.x * 256 + threadIdx.x;
  if (t < 16384) { int r = t >> 7, c = t & 127; W1lT[c * 128 + r] = W1l[t]; }
  else if (t < 32768) { int u = t - 16384; int r = u >> 7, c = u & 127; W1rT[c * 128 + r] = W1r[u]; }
  else if (t < 40960) { int u = t - 32768; int r = u >> 6, c = u & 63; W2lT[c * 128 + r] = W2l[u]; }
  else if (t < 49152) { int u = t - 40960; int r = u >> 6, c = u & 63; W2rT[c * 128 + r] = W2r[u]; }
}

extern "C" void kernel_launch(void* const* d_in, const int* in_sizes, int n_in,
                              void* d_out, int out_size, void* d_ws, size_t ws_size,
                              hipStream_t stream)
{
  const float* x   = (const float*)d_in[0];
  const int*   ei  = (const int*)d_in[1];
  const float* W1l = (const float*)d_in[2];
  const float* b1l = (const float*)d_in[3];
  const float* W1r = (const float*)d_in[4];
  const float* W2l = (const float*)d_in[5];
  const float* b2l = (const float*)d_in[6];
  const float* W2r = (const float*)d_in[7];
  float* out = (float*)d_out;

  const int n_nodes = in_sizes[0] / D;   // 50000
  const int n_edges = in_sizes[1] / 2;   // 600000
  const int* src = ei;
  const int* dst = ei + n_edges;

  char* ws = (char*)d_ws;
  auto align256 = [](size_t v) { return (v + 255) & ~(size_t)255; };
  const size_t szN  = align256((size_t)n_nodes * 4);
  const size_t szN1 = align256(((size_t)n_nodes + 1) * 4);
  const size_t szE  = align256((size_t)n_edges * 4);

  size_t o = 0;
  int*   deg    = (int*)(ws + o);   o += szN;
  int*   cursor = (int*)(ws + o);   o += szN;
  int*   off    = (int*)(ws + o);   o += szN1;
  float* invdeg = (float*)(ws + o); o += szN;
  int*   eidx   = (int*)(ws + o);   o += szE;
  float* W1lT   = (float*)(ws + o); o += 128 * 128 * 4;
  float* W1rT   = (float*)(ws + o); o += 128 * 128 * 4;
  float* W2lT   = (float*)(ws + o); o += 128 * 64 * 4;
  float* W2rT   = (float*)(ws + o); o += 128 * 64 * 4;
  float* mean   = (float*)(ws + o); o += (size_t)n_nodes * D * 4;  // reused as aggmean (64-wide)
  float* h      = (float*)(ws + o); o += (size_t)n_nodes * D * 4;
  float* hl     = (float*)(ws + o); o += (size_t)n_nodes * O2 * 4;
  float* aggmean = mean;  // mean is dead after layer1; alias

  hipMemsetAsync(deg, 0, szN, stream);

  transpose_w<<<192, 256, 0, stream>>>(W1l, W1r, W2l, W2r, W1lT, W1rT, W2lT, W2rT);

  // CSR by dst
  hist_kernel<<<(n_edges + 255) / 256, 256, 0, stream>>>(dst, deg, n_edges);
  scan_kernel<<<1, 1024, 0, stream>>>(deg, off, cursor, invdeg, n_nodes);
  fill_kernel<<<(n_edges + 255) / 256, 256, 0, stream>>>(src, dst, cursor, eidx, n_edges);

  // layer 1: mean aggregate (gather), then fused GEMM
  gather_mean_kernel<32><<<(n_nodes + 7) / 8, 256, 0, stream>>>(
      x, eidx, off, invdeg, mean, n_nodes);
  layer1_kernel<<<(n_nodes + 31) / 32, 256, 0, stream>>>(
      x, mean, W1lT, b1l, W1rT, h, n_nodes);

  // layer 2: push matmul before aggregation (linearity), gather 64-wide
  gemm64_kernel<false><<<(n_nodes + 63) / 64, 256, 0, stream>>>(
      h, W2lT, nullptr, nullptr, hl, n_nodes);
  gather_mean_kernel<16><<<(n_nodes + 15) / 16, 256, 0, stream>>>(
      hl, eidx, off, invdeg, aggmean, n_nodes);
  gemm64_kernel<true><<<(n_nodes + 63) / 64, 256, 0, stream>>>(
      h, W2rT, b2l, aggmean, out, n_nodes);
}

// Round 3
// 387.834 us; speedup vs baseline: 4.8040x; 1.4633x over previous
//
#include <hip/hip_runtime.h>
#include <cstdint>
#include <cstddef>

#define D 128
#define O2 64

typedef __attribute__((ext_vector_type(8))) short bf16x8;
typedef __attribute__((ext_vector_type(4))) float f32x4;

__device__ inline unsigned short f2bf(float f) {
  union { float f; uint32_t u; } v; v.f = f;
  uint32_t r = v.u + 0x7FFF + ((v.u >> 16) & 1);
  return (unsigned short)(r >> 16);
}
__device__ inline float bf_lo(uint32_t w) {
  union { uint32_t u; float f; } v; v.u = w << 16; return v.f;
}
__device__ inline float bf_hi(uint32_t w) {
  union { uint32_t u; float f; } v; v.u = w & 0xFFFF0000u; return v.f;
}

// ---------------- prep: x->bf16 into A1[:,128:256], weight transpose+cast, degree hist ----------------
__global__ __launch_bounds__(256) void prep_kernel(
    const float* __restrict__ x, const float* __restrict__ W1l,
    const float* __restrict__ W1r, const float* __restrict__ W2l,
    const float* __restrict__ W2r, const int* __restrict__ dst,
    unsigned short* __restrict__ A1, unsigned short* __restrict__ WT1,
    unsigned short* __restrict__ WT2, int* __restrict__ deg,
    int n_nodes, int n_edges, int xb_blocks, int w_blocks)
{
  int b = blockIdx.x;
  if (b < xb_blocks) {
    int i = b * 256 + threadIdx.x;            // float4 index into x
    if (i < n_nodes * 32) {
      int n = i >> 5, q = i & 31;
      float4 v = ((const float4*)x)[(size_t)n * 32 + q];
      ushort4 o;
      o.x = f2bf(v.x); o.y = f2bf(v.y); o.z = f2bf(v.z); o.w = f2bf(v.w);
      *(ushort4*)(A1 + (size_t)n * 256 + 128 + q * 4) = o;
    }
  } else if (b < xb_blocks + w_blocks) {
    int t = (b - xb_blocks) * 256 + threadIdx.x;
    if (t < 128 * 256) {                      // WT1[n][k], k<128 from W1l, else W1r
      int n = t >> 8, k = t & 255;
      float w = (k < 128) ? W1l[(size_t)k * 128 + n] : W1r[(size_t)(k - 128) * 128 + n];
      WT1[t] = f2bf(w);
    } else {
      int u = t - 128 * 256;
      if (u < 128 * 128) {                    // WT2[n][k], n<64 from W2l, else W2r
        int n = u >> 7, k = u & 127;
        float w = (n < 64) ? W2l[(size_t)k * 64 + n] : W2r[(size_t)k * 64 + (n - 64)];
        WT2[u] = f2bf(w);
      }
    }
  } else {
    int e = (b - xb_blocks - w_blocks) * 256 + threadIdx.x;
    if (e < n_edges) atomicAdd(&deg[dst[e]], 1);
  }
}

// ---------------- CSR: scan + fill ----------------
__global__ __launch_bounds__(1024) void scan_kernel(
    const int* __restrict__ deg, int* __restrict__ off, int* __restrict__ cursor,
    float* __restrict__ invdeg, int n_nodes)
{
  __shared__ int part[1024];
  const int t = threadIdx.x;
  const int chunk = (n_nodes + 1023) / 1024;
  const int lo = t * chunk;
  const int hi = min(lo + chunk, n_nodes);
  int s = 0;
  for (int i = lo; i < hi; i++) s += deg[i];
  part[t] = s;
  __syncthreads();
  for (int d = 1; d < 1024; d <<= 1) {
    int v = (t >= d) ? part[t - d] : 0;
    __syncthreads();
    part[t] += v;
    __syncthreads();
  }
  int run = (t == 0) ? 0 : part[t - 1];
  for (int i = lo; i < hi; i++) {
    off[i] = run; cursor[i] = run;
    int dg = deg[i];
    invdeg[i] = 1.0f / fmaxf((float)dg, 1.0f);
    run += dg;
  }
  if (t == 1023) off[n_nodes] = run;
}

__global__ __launch_bounds__(256) void fill_kernel(
    const int* __restrict__ src, const int* __restrict__ dst,
    int* __restrict__ cursor, int* __restrict__ eidx, int n_edges)
{
  int e = blockIdx.x * 256 + threadIdx.x;
  if (e < n_edges) {
    int p = atomicAdd(&cursor[dst[e]], 1);
    eidx[p] = src[e];
  }
}

// ---------------- gather1: mean of neighbor xb into A1[:,0:128] (bf16) ----------------
__global__ __launch_bounds__(256) void gather1_kernel(
    unsigned short* __restrict__ A1, const int* __restrict__ eidx,
    const int* __restrict__ off, const float* __restrict__ invdeg, int n_nodes)
{
  int g = threadIdx.x >> 4;          // 16 nodes/block
  int j = threadIdx.x & 15;          // cols j*8 .. j*8+7
  int n = blockIdx.x * 16 + g;
  if (n >= n_nodes) return;
  int lo = off[n], hi = off[n + 1];
  float a0=0,a1=0,a2=0,a3=0,a4=0,a5=0,a6=0,a7=0;
  for (int p = lo; p < hi; p++) {
    int s = eidx[p];
    uint4 v = *(const uint4*)(A1 + (size_t)s * 256 + 128 + j * 8);
    a0 += bf_lo(v.x); a1 += bf_hi(v.x);
    a2 += bf_lo(v.y); a3 += bf_hi(v.y);
    a4 += bf_lo(v.z); a5 += bf_hi(v.z);
    a6 += bf_lo(v.w); a7 += bf_hi(v.w);
  }
  float ic = invdeg[n];
  uint4 o;
  o.x = ((uint32_t)f2bf(a1 * ic) << 16) | f2bf(a0 * ic);
  o.y = ((uint32_t)f2bf(a3 * ic) << 16) | f2bf(a2 * ic);
  o.z = ((uint32_t)f2bf(a5 * ic) << 16) | f2bf(a4 * ic);
  o.w = ((uint32_t)f2bf(a7 * ic) << 16) | f2bf(a6 * ic);
  *(uint4*)(A1 + (size_t)n * 256 + j * 8) = o;
}

// ---------------- layer1 MFMA: h = relu(A1 @ WT1^T + b1l), K=256, N=128 ----------------
__global__ __launch_bounds__(256) void layer1_mfma(
    const unsigned short* __restrict__ A1, const unsigned short* __restrict__ WT1,
    const float* __restrict__ b1l, unsigned short* __restrict__ h, int n_nodes)
{
  const int wave = threadIdx.x >> 6, lane = threadIdx.x & 63;
  const int quad = lane >> 4, l15 = lane & 15;
  const int R0 = blockIdx.x * 64 + wave * 16;
  const int ra = min(R0 + l15, n_nodes - 1);
  bf16x8 af[8];
  const unsigned short* arow = A1 + (size_t)ra * 256 + quad * 8;
  #pragma unroll
  for (int s = 0; s < 8; s++) af[s] = *(const bf16x8*)(arow + s * 32);
  f32x4 acc[8];
  #pragma unroll
  for (int t = 0; t < 8; t++) acc[t] = (f32x4){0.f, 0.f, 0.f, 0.f};
  const unsigned short* bbase = WT1 + (size_t)l15 * 256 + quad * 8;
  #pragma unroll
  for (int s = 0; s < 8; s++) {
    #pragma unroll
    for (int t = 0; t < 8; t++) {
      bf16x8 bf = *(const bf16x8*)(bbase + (size_t)t * 16 * 256 + s * 32);
      acc[t] = __builtin_amdgcn_mfma_f32_16x16x32_bf16(af[s], bf, acc[t], 0, 0, 0);
    }
  }
  const int rowb = R0 + quad * 4;
  #pragma unroll
  for (int t = 0; t < 8; t++) {
    int col = t * 16 + l15;
    float bias = b1l[col];
    #pragma unroll
    for (int r = 0; r < 4; r++) {
      int row = rowb + r;
      if (row < n_nodes)
        h[(size_t)row * 128 + col] = f2bf(fmaxf(acc[t][r] + bias, 0.f));
    }
  }
}

// ---------------- layer2 MFMA: [hl | pre] = h @ WT2^T, K=128, N=128 ----------------
// cols 0..63 -> hl (bf16), cols 64..127 -> out (fp32, pre-epilogue)
__global__ __launch_bounds__(256) void layer2_mfma(
    const unsigned short* __restrict__ h, const unsigned short* __restrict__ WT2,
    unsigned short* __restrict__ hl, float* __restrict__ outp, int n_nodes)
{
  const int wave = threadIdx.x >> 6, lane = threadIdx.x & 63;
  const int quad = lane >> 4, l15 = lane & 15;
  const int R0 = blockIdx.x * 64 + wave * 16;
  const int ra = min(R0 + l15, n_nodes - 1);
  bf16x8 af[4];
  const unsigned short* arow = h + (size_t)ra * 128 + quad * 8;
  #pragma unroll
  for (int s = 0; s < 4; s++) af[s] = *(const bf16x8*)(arow + s * 32);
  f32x4 acc[8];
  #pragma unroll
  for (int t = 0; t < 8; t++) acc[t] = (f32x4){0.f, 0.f, 0.f, 0.f};
  const unsigned short* bbase = WT2 + (size_t)l15 * 128 + quad * 8;
  #pragma unroll
  for (int s = 0; s < 4; s++) {
    #pragma unroll
    for (int t = 0; t < 8; t++) {
      bf16x8 bf = *(const bf16x8*)(bbase + (size_t)t * 16 * 128 + s * 32);
      acc[t] = __builtin_amdgcn_mfma_f32_16x16x32_bf16(af[s], bf, acc[t], 0, 0, 0);
    }
  }
  const int rowb = R0 + quad * 4;
  #pragma unroll
  for (int t = 0; t < 8; t++) {
    int col = t * 16 + l15;
    #pragma unroll
    for (int r = 0; r < 4; r++) {
      int row = rowb + r;
      if (row < n_nodes) {
        if (t < 4) hl[(size_t)row * 64 + col] = f2bf(acc[t][r]);
        else       outp[(size_t)row * 64 + (col - 64)] = acc[t][r];
      }
    }
  }
}

// ---------------- gather2: out += b2l + mean of neighbor hl ----------------
__global__ __launch_bounds__(256) void gather2_kernel(
    const unsigned short* __restrict__ hl, const int* __restrict__ eidx,
    const int* __restrict__ off, const float* __restrict__ invdeg,
    const float* __restrict__ b2l, float* __restrict__ out, int n_nodes)
{
  int g = threadIdx.x >> 3;          // 32 nodes/block
  int j = threadIdx.x & 7;           // cols j*8 .. j*8+7
  int n = blockIdx.x * 32 + g;
  if (n >= n_nodes) return;
  int lo = off[n], hi = off[n + 1];
  float a0=0,a1=0,a2=0,a3=0,a4=0,a5=0,a6=0,a7=0;
  for (int p = lo; p < hi; p++) {
    int s = eidx[p];
    uint4 v = *(const uint4*)(hl + (size_t)s * 64 + j * 8);
    a0 += bf_lo(v.x); a1 += bf_hi(v.x);
    a2 += bf_lo(v.y); a3 += bf_hi(v.y);
    a4 += bf_lo(v.z); a5 += bf_hi(v.z);
    a6 += bf_lo(v.w); a7 += bf_hi(v.w);
  }
  float ic = invdeg[n];
  float* o = out + (size_t)n * 64 + j * 8;
  const float* bb = b2l + j * 8;
  float4 p0 = *(const float4*)(o);
  float4 p1 = *(const float4*)(o + 4);
  p0.x += bb[0] + a0 * ic; p0.y += bb[1] + a1 * ic;
  p0.z += bb[2] + a2 * ic; p0.w += bb[3] + a3 * ic;
  p1.x += bb[4] + a4 * ic; p1.y += bb[5] + a5 * ic;
  p1.z += bb[6] + a6 * ic; p1.w += bb[7] + a7 * ic;
  *(float4*)(o) = p0;
  *(float4*)(o + 4) = p1;
}

extern "C" void kernel_launch(void* const* d_in, const int* in_sizes, int n_in,
                              void* d_out, int out_size, void* d_ws, size_t ws_size,
                              hipStream_t stream)
{
  const float* x   = (const float*)d_in[0];
  const int*   ei  = (const int*)d_in[1];
  const float* W1l = (const float*)d_in[2];
  const float* b1l = (const float*)d_in[3];
  const float* W1r = (const float*)d_in[4];
  const float* W2l = (const float*)d_in[5];
  const float* b2l = (const float*)d_in[6];
  const float* W2r = (const float*)d_in[7];
  float* out = (float*)d_out;

  const int n_nodes = in_sizes[0] / D;   // 50000
  const int n_edges = in_sizes[1] / 2;   // 600000
  const int* src = ei;
  const int* dst = ei + n_edges;

  char* ws = (char*)d_ws;
  auto align256 = [](size_t v) { return (v + 255) & ~(size_t)255; };
  const size_t szN  = align256((size_t)n_nodes * 4);
  const size_t szN1 = align256(((size_t)n_nodes + 1) * 4);
  const size_t szE  = align256((size_t)n_edges * 4);

  size_t o = 0;
  int*   deg    = (int*)(ws + o);   o += szN;
  int*   cursor = (int*)(ws + o);   o += szN;
  int*   off    = (int*)(ws + o);   o += szN1;
  float* invdeg = (float*)(ws + o); o += szN;
  int*   eidx   = (int*)(ws + o);   o += szE;
  unsigned short* WT1 = (unsigned short*)(ws + o); o += align256(128 * 256 * 2);
  unsigned short* WT2 = (unsigned short*)(ws + o); o += align256(128 * 128 * 2);
  unsigned short* A1  = (unsigned short*)(ws + o); o += align256((size_t)n_nodes * 256 * 2);
  unsigned short* h   = (unsigned short*)(ws + o); o += align256((size_t)n_nodes * 128 * 2);
  unsigned short* hl  = (unsigned short*)(ws + o); o += align256((size_t)n_nodes * 64 * 2);

  hipMemsetAsync(deg, 0, szN, stream);

  const int xb_blocks = (n_nodes * 32 + 255) / 256;            // 6250
  const int w_blocks  = (128 * 256 + 128 * 128 + 255) / 256;   // 192
  const int e_blocks  = (n_edges + 255) / 256;                 // 2344
  prep_kernel<<<xb_blocks + w_blocks + e_blocks, 256, 0, stream>>>(
      x, W1l, W1r, W2l, W2r, dst, A1, WT1, WT2, deg,
      n_nodes, n_edges, xb_blocks, w_blocks);

  scan_kernel<<<1, 1024, 0, stream>>>(deg, off, cursor, invdeg, n_nodes);
  fill_kernel<<<e_blocks, 256, 0, stream>>>(src, dst, cursor, eidx, n_edges);

  gather1_kernel<<<(n_nodes + 15) / 16, 256, 0, stream>>>(A1, eidx, off, invdeg, n_nodes);
  layer1_mfma<<<(n_nodes + 63) / 64, 256, 0, stream>>>(A1, WT1, b1l, h, n_nodes);
  layer2_mfma<<<(n_nodes + 63) / 64, 256, 0, stream>>>(h, WT2, hl, out, n_nodes);
  gather2_kernel<<<(n_nodes + 31) / 32, 256, 0, stream>>>(hl, eidx, off, invdeg, b2l, out, n_nodes);
}

// Round 4
// 264.235 us; speedup vs baseline: 7.0511x; 1.4678x over previous
//
#include <hip/hip_runtime.h>
#include <cstdint>
#include <cstddef>

#define D 128
#define O2 64

typedef __attribute__((ext_vector_type(8))) short bf16x8;
typedef __attribute__((ext_vector_type(4))) float f32x4;

__device__ inline unsigned short f2bf(float f) {
  union { float f; uint32_t u; } v; v.f = f;
  uint32_t r = v.u + 0x7FFF + ((v.u >> 16) & 1);
  return (unsigned short)(r >> 16);
}
__device__ inline float bf_lo(uint32_t w) {
  union { uint32_t u; float f; } v; v.u = w << 16; return v.f;
}
__device__ inline float bf_hi(uint32_t w) {
  union { uint32_t u; float f; } v; v.u = w & 0xFFFF0000u; return v.f;
}

// ---------------- prep: x->bf16 into A1[:,128:256], weight transpose+cast, degree hist ----------------
__global__ __launch_bounds__(256) void prep_kernel(
    const float* __restrict__ x, const float* __restrict__ W1l,
    const float* __restrict__ W1r, const float* __restrict__ W2l,
    const float* __restrict__ W2r, const int* __restrict__ dst,
    unsigned short* __restrict__ A1, unsigned short* __restrict__ WT1,
    unsigned short* __restrict__ WT2, int* __restrict__ deg,
    int n_nodes, int n_edges, int xb_blocks, int w_blocks)
{
  int b = blockIdx.x;
  if (b < xb_blocks) {
    int i = b * 256 + threadIdx.x;            // float4 index into x
    if (i < n_nodes * 32) {
      int n = i >> 5, q = i & 31;
      float4 v = ((const float4*)x)[(size_t)n * 32 + q];
      ushort4 o;
      o.x = f2bf(v.x); o.y = f2bf(v.y); o.z = f2bf(v.z); o.w = f2bf(v.w);
      *(ushort4*)(A1 + (size_t)n * 256 + 128 + q * 4) = o;
    }
  } else if (b < xb_blocks + w_blocks) {
    int t = (b - xb_blocks) * 256 + threadIdx.x;
    if (t < 128 * 256) {                      // WT1[n][k], k<128 from W1l, else W1r
      int n = t >> 8, k = t & 255;
      float w = (k < 128) ? W1l[(size_t)k * 128 + n] : W1r[(size_t)(k - 128) * 128 + n];
      WT1[t] = f2bf(w);
    } else {
      int u = t - 128 * 256;
      if (u < 128 * 128) {                    // WT2[n][k], n<64 from W2l, else W2r
        int n = u >> 7, k = u & 127;
        float w = (n < 64) ? W2l[(size_t)k * 64 + n] : W2r[(size_t)k * 64 + (n - 64)];
        WT2[u] = f2bf(w);
      }
    }
  } else {
    int e = (b - xb_blocks - w_blocks) * 256 + threadIdx.x;
    if (e < n_edges) atomicAdd(&deg[dst[e]], 1);
  }
}

// ---------------- hierarchical scan: partials -> scan partials -> emit ----------------
__global__ __launch_bounds__(256) void partial_kernel(
    const int* __restrict__ deg, int* __restrict__ part, int n_nodes)
{
  __shared__ int red[256];
  int t = threadIdx.x;
  int i = blockIdx.x * 256 + t;
  red[t] = (i < n_nodes) ? deg[i] : 0;
  __syncthreads();
  for (int d = 128; d > 0; d >>= 1) {
    if (t < d) red[t] += red[t + d];
    __syncthreads();
  }
  if (t == 0) part[blockIdx.x] = red[0];
}

__global__ __launch_bounds__(256) void scanp_kernel(int* __restrict__ part, int nb)
{
  __shared__ int s[256];
  int t = threadIdx.x;
  s[t] = (t < nb) ? part[t] : 0;
  __syncthreads();
  for (int d = 1; d < 256; d <<= 1) {
    int v = (t >= d) ? s[t - d] : 0;
    __syncthreads();
    s[t] += v;
    __syncthreads();
  }
  if (t < nb) part[t] = (t == 0) ? 0 : s[t - 1];
}

__global__ __launch_bounds__(256) void emit_kernel(
    const int* __restrict__ deg, const int* __restrict__ part,
    int* __restrict__ off, int* __restrict__ cursor,
    float* __restrict__ invdeg, int n_nodes)
{
  __shared__ int s[256];
  int t = threadIdx.x;
  int i = blockIdx.x * 256 + t;
  int dg = (i < n_nodes) ? deg[i] : 0;
  s[t] = dg;
  __syncthreads();
  for (int d = 1; d < 256; d <<= 1) {
    int v = (t >= d) ? s[t - d] : 0;
    __syncthreads();
    s[t] += v;
    __syncthreads();
  }
  int excl = part[blockIdx.x] + s[t] - dg;
  if (i < n_nodes) {
    off[i] = excl;
    cursor[i] = excl;
    invdeg[i] = 1.0f / fmaxf((float)dg, 1.0f);
    if (i == n_nodes - 1) off[n_nodes] = excl + dg;
  }
}

__global__ __launch_bounds__(256) void fill_kernel(
    const int* __restrict__ src, const int* __restrict__ dst,
    int* __restrict__ cursor, int* __restrict__ eidx, int n_edges)
{
  int e = blockIdx.x * 256 + threadIdx.x;
  if (e < n_edges) {
    int p = atomicAdd(&cursor[dst[e]], 1);
    eidx[p] = src[e];
  }
}

// ---------------- gather1: mean of neighbor xb into A1[:,0:128] (bf16) ----------------
__global__ __launch_bounds__(256) void gather1_kernel(
    unsigned short* __restrict__ A1, const int* __restrict__ eidx,
    const int* __restrict__ off, const float* __restrict__ invdeg, int n_nodes)
{
  int g = threadIdx.x >> 4;          // 16 nodes/block
  int j = threadIdx.x & 15;          // cols j*8 .. j*8+7
  int n = blockIdx.x * 16 + g;
  if (n >= n_nodes) return;
  int lo = off[n], hi = off[n + 1];
  float a0=0,a1=0,a2=0,a3=0,a4=0,a5=0,a6=0,a7=0;
  for (int p = lo; p < hi; p++) {
    int s = eidx[p];
    uint4 v = *(const uint4*)(A1 + (size_t)s * 256 + 128 + j * 8);
    a0 += bf_lo(v.x); a1 += bf_hi(v.x);
    a2 += bf_lo(v.y); a3 += bf_hi(v.y);
    a4 += bf_lo(v.z); a5 += bf_hi(v.z);
    a6 += bf_lo(v.w); a7 += bf_hi(v.w);
  }
  float ic = invdeg[n];
  uint4 o;
  o.x = ((uint32_t)f2bf(a1 * ic) << 16) | f2bf(a0 * ic);
  o.y = ((uint32_t)f2bf(a3 * ic) << 16) | f2bf(a2 * ic);
  o.z = ((uint32_t)f2bf(a5 * ic) << 16) | f2bf(a4 * ic);
  o.w = ((uint32_t)f2bf(a7 * ic) << 16) | f2bf(a6 * ic);
  *(uint4*)(A1 + (size_t)n * 256 + j * 8) = o;
}

// ---------------- layer1 MFMA: h = relu(A1 @ WT1^T + b1l), K=256, N=128 ----------------
__global__ __launch_bounds__(256) void layer1_mfma(
    const unsigned short* __restrict__ A1, const unsigned short* __restrict__ WT1,
    const float* __restrict__ b1l, unsigned short* __restrict__ h, int n_nodes)
{
  const int wave = threadIdx.x >> 6, lane = threadIdx.x & 63;
  const int quad = lane >> 4, l15 = lane & 15;
  const int R0 = blockIdx.x * 64 + wave * 16;
  const int ra = min(R0 + l15, n_nodes - 1);
  bf16x8 af[8];
  const unsigned short* arow = A1 + (size_t)ra * 256 + quad * 8;
  #pragma unroll
  for (int s = 0; s < 8; s++) af[s] = *(const bf16x8*)(arow + s * 32);
  f32x4 acc[8];
  #pragma unroll
  for (int t = 0; t < 8; t++) acc[t] = (f32x4){0.f, 0.f, 0.f, 0.f};
  const unsigned short* bbase = WT1 + (size_t)l15 * 256 + quad * 8;
  #pragma unroll
  for (int s = 0; s < 8; s++) {
    #pragma unroll
    for (int t = 0; t < 8; t++) {
      bf16x8 bf = *(const bf16x8*)(bbase + (size_t)t * 16 * 256 + s * 32);
      acc[t] = __builtin_amdgcn_mfma_f32_16x16x32_bf16(af[s], bf, acc[t], 0, 0, 0);
    }
  }
  const int rowb = R0 + quad * 4;
  #pragma unroll
  for (int t = 0; t < 8; t++) {
    int col = t * 16 + l15;
    float bias = b1l[col];
    #pragma unroll
    for (int r = 0; r < 4; r++) {
      int row = rowb + r;
      if (row < n_nodes)
        h[(size_t)row * 128 + col] = f2bf(fmaxf(acc[t][r] + bias, 0.f));
    }
  }
}

// ---------------- layer2 MFMA: [hl | pre] = h @ WT2^T, K=128, N=128 ----------------
// cols 0..63 -> hl (bf16), cols 64..127 -> out (fp32, pre-epilogue)
__global__ __launch_bounds__(256) void layer2_mfma(
    const unsigned short* __restrict__ h, const unsigned short* __restrict__ WT2,
    unsigned short* __restrict__ hl, float* __restrict__ outp, int n_nodes)
{
  const int wave = threadIdx.x >> 6, lane = threadIdx.x & 63;
  const int quad = lane >> 4, l15 = lane & 15;
  const int R0 = blockIdx.x * 64 + wave * 16;
  const int ra = min(R0 + l15, n_nodes - 1);
  bf16x8 af[4];
  const unsigned short* arow = h + (size_t)ra * 128 + quad * 8;
  #pragma unroll
  for (int s = 0; s < 4; s++) af[s] = *(const bf16x8*)(arow + s * 32);
  f32x4 acc[8];
  #pragma unroll
  for (int t = 0; t < 8; t++) acc[t] = (f32x4){0.f, 0.f, 0.f, 0.f};
  const unsigned short* bbase = WT2 + (size_t)l15 * 128 + quad * 8;
  #pragma unroll
  for (int s = 0; s < 4; s++) {
    #pragma unroll
    for (int t = 0; t < 8; t++) {
      bf16x8 bf = *(const bf16x8*)(bbase + (size_t)t * 16 * 128 + s * 32);
      acc[t] = __builtin_amdgcn_mfma_f32_16x16x32_bf16(af[s], bf, acc[t], 0, 0, 0);
    }
  }
  const int rowb = R0 + quad * 4;
  #pragma unroll
  for (int t = 0; t < 8; t++) {
    int col = t * 16 + l15;
    #pragma unroll
    for (int r = 0; r < 4; r++) {
      int row = rowb + r;
      if (row < n_nodes) {
        if (t < 4) hl[(size_t)row * 64 + col] = f2bf(acc[t][r]);
        else       outp[(size_t)row * 64 + (col - 64)] = acc[t][r];
      }
    }
  }
}

// ---------------- gather2: out += b2l + mean of neighbor hl ----------------
__global__ __launch_bounds__(256) void gather2_kernel(
    const unsigned short* __restrict__ hl, const int* __restrict__ eidx,
    const int* __restrict__ off, const float* __restrict__ invdeg,
    const float* __restrict__ b2l, float* __restrict__ out, int n_nodes)
{
  int g = threadIdx.x >> 3;          // 32 nodes/block
  int j = threadIdx.x & 7;           // cols j*8 .. j*8+7
  int n = blockIdx.x * 32 + g;
  if (n >= n_nodes) return;
  int lo = off[n], hi = off[n + 1];
  float a0=0,a1=0,a2=0,a3=0,a4=0,a5=0,a6=0,a7=0;
  for (int p = lo; p < hi; p++) {
    int s = eidx[p];
    uint4 v = *(const uint4*)(hl + (size_t)s * 64 + j * 8);
    a0 += bf_lo(v.x); a1 += bf_hi(v.x);
    a2 += bf_lo(v.y); a3 += bf_hi(v.y);
    a4 += bf_lo(v.z); a5 += bf_hi(v.z);
    a6 += bf_lo(v.w); a7 += bf_hi(v.w);
  }
  float ic = invdeg[n];
  float* o = out + (size_t)n * 64 + j * 8;
  const float* bb = b2l + j * 8;
  float4 p0 = *(const float4*)(o);
  float4 p1 = *(const float4*)(o + 4);
  p0.x += bb[0] + a0 * ic; p0.y += bb[1] + a1 * ic;
  p0.z += bb[2] + a2 * ic; p0.w += bb[3] + a3 * ic;
  p1.x += bb[4] + a4 * ic; p1.y += bb[5] + a5 * ic;
  p1.z += bb[6] + a6 * ic; p1.w += bb[7] + a7 * ic;
  *(float4*)(o) = p0;
  *(float4*)(o + 4) = p1;
}

extern "C" void kernel_launch(void* const* d_in, const int* in_sizes, int n_in,
                              void* d_out, int out_size, void* d_ws, size_t ws_size,
                              hipStream_t stream)
{
  const float* x   = (const float*)d_in[0];
  const int*   ei  = (const int*)d_in[1];
  const float* W1l = (const float*)d_in[2];
  const float* b1l = (const float*)d_in[3];
  const float* W1r = (const float*)d_in[4];
  const float* W2l = (const float*)d_in[5];
  const float* b2l = (const float*)d_in[6];
  const float* W2r = (const float*)d_in[7];
  float* out = (float*)d_out;

  const int n_nodes = in_sizes[0] / D;   // 50000
  const int n_edges = in_sizes[1] / 2;   // 600000
  const int* src = ei;
  const int* dst = ei + n_edges;

  char* ws = (char*)d_ws;
  auto align256 = [](size_t v) { return (v + 255) & ~(size_t)255; };
  const size_t szN  = align256((size_t)n_nodes * 4);
  const size_t szN1 = align256(((size_t)n_nodes + 1) * 4);
  const size_t szE  = align256((size_t)n_edges * 4);
  const int nb = (n_nodes + 255) / 256;   // 196 scan blocks

  size_t o = 0;
  int*   deg    = (int*)(ws + o);   o += szN;
  int*   cursor = (int*)(ws + o);   o += szN;
  int*   off    = (int*)(ws + o);   o += szN1;
  float* invdeg = (float*)(ws + o); o += szN;
  int*   part   = (int*)(ws + o);   o += align256((size_t)nb * 4);
  int*   eidx   = (int*)(ws + o);   o += szE;
  unsigned short* WT1 = (unsigned short*)(ws + o); o += align256(128 * 256 * 2);
  unsigned short* WT2 = (unsigned short*)(ws + o); o += align256(128 * 128 * 2);
  unsigned short* A1  = (unsigned short*)(ws + o); o += align256((size_t)n_nodes * 256 * 2);
  unsigned short* h   = (unsigned short*)(ws + o); o += align256((size_t)n_nodes * 128 * 2);
  unsigned short* hl  = (unsigned short*)(ws + o); o += align256((size_t)n_nodes * 64 * 2);

  hipMemsetAsync(deg, 0, szN, stream);

  const int xb_blocks = (n_nodes * 32 + 255) / 256;            // 6250
  const int w_blocks  = (128 * 256 + 128 * 128 + 255) / 256;   // 192
  const int e_blocks  = (n_edges + 255) / 256;                 // 2344
  prep_kernel<<<xb_blocks + w_blocks + e_blocks, 256, 0, stream>>>(
      x, W1l, W1r, W2l, W2r, dst, A1, WT1, WT2, deg,
      n_nodes, n_edges, xb_blocks, w_blocks);

  // hierarchical exclusive scan of deg -> off/cursor/invdeg
  partial_kernel<<<nb, 256, 0, stream>>>(deg, part, n_nodes);
  scanp_kernel<<<1, 256, 0, stream>>>(part, nb);
  emit_kernel<<<nb, 256, 0, stream>>>(deg, part, off, cursor, invdeg, n_nodes);

  fill_kernel<<<e_blocks, 256, 0, stream>>>(src, dst, cursor, eidx, n_edges);

  gather1_kernel<<<(n_nodes + 15) / 16, 256, 0, stream>>>(A1, eidx, off, invdeg, n_nodes);
  layer1_mfma<<<(n_nodes + 63) / 64, 256, 0, stream>>>(A1, WT1, b1l, h, n_nodes);
  layer2_mfma<<<(n_nodes + 63) / 64, 256, 0, stream>>>(h, WT2, hl, out, n_nodes);
  gather2_kernel<<<(n_nodes + 31) / 32, 256, 0, stream>>>(hl, eidx, off, invdeg, b2l, out, n_nodes);
}